// Round 2
// baseline (77.709 us; speedup 1.0000x reference)
//
#include <hip/hip_runtime.h>
#include <hip/hip_bf16.h>
#include <cmath>

typedef __attribute__((ext_vector_type(8))) short short8;
typedef __attribute__((ext_vector_type(4))) float f32x4;

#define EPS_F 1e-7f
#define NEG_DIAG_F -10.0f

__device__ __forceinline__ unsigned enc_f32(float f) {
    unsigned u = __float_as_uint(f);
    return (u & 0x80000000u) ? ~u : (u | 0x80000000u);
}
__device__ __forceinline__ float dec_f32(unsigned u) {
    return (u & 0x80000000u) ? __uint_as_float(u ^ 0x80000000u) : __uint_as_float(~u);
}

__device__ __forceinline__ void gload_lds16(const void* gptr, void* ldsptr) {
    __builtin_amdgcn_global_load_lds(
        (const __attribute__((address_space(1))) unsigned int*)gptr,
        (__attribute__((address_space(3))) unsigned int*)ldsptr,
        16, 0, 0);
}

// ---------------------------------------------------------------------------
// Kernel 1: row L2-normalize feat_k / feat_g (in f32), cast to bf16,
// zero the row-max array. One block (D=256 threads) per row.
// ---------------------------------------------------------------------------
__global__ void norm_cast_kernel(const float* __restrict__ fk, const float* __restrict__ fg,
                                 __hip_bfloat16* __restrict__ fkb, __hip_bfloat16* __restrict__ fgb,
                                 unsigned* __restrict__ rowmax, int N, int D) {
    int n = blockIdx.x;
    int t = threadIdx.x;
    float xk = fk[(size_t)n * D + t];
    float xg = fg[(size_t)n * D + t];
    float sk = xk * xk, sg = xg * xg;
#pragma unroll
    for (int off = 32; off > 0; off >>= 1) {
        sk += __shfl_xor(sk, off, 64);
        sg += __shfl_xor(sg, off, 64);
    }
    __shared__ float lsk[4], lsg[4];
    int w = t >> 6, l = t & 63;
    if (l == 0) { lsk[w] = sk; lsg[w] = sg; }
    __syncthreads();
    sk = lsk[0] + lsk[1] + lsk[2] + lsk[3];
    sg = lsg[0] + lsg[1] + lsg[2] + lsg[3];
    float rkv = 1.0f / (sqrtf(sk) + EPS_F);
    float rgv = 1.0f / (sqrtf(sg) + EPS_F);
    fkb[(size_t)n * D + t] = __float2bfloat16(xk * rkv);
    fgb[(size_t)n * D + t] = __float2bfloat16(xg * rgv);
    if (t == 0) rowmax[n] = 0u;
}

// ---------------------------------------------------------------------------
// Kernel 2: fused dual Gram GEMM (bf16 MFMA).  s = (dk+1+eps)/(dg+1+eps),
// diag = -10, write s to out, atomicMax row max (order-preserving encoding).
// Tile 128x128, BK=64, 8 waves (2x4), 64 KB LDS, XOR-swizzled staging.
// ---------------------------------------------------------------------------
#define BM 128
#define BN 128
#define BK 64
#define NTHREADS 512

__global__ __launch_bounds__(NTHREADS) void dual_gram_kernel(
    const __hip_bfloat16* __restrict__ fkb, const __hip_bfloat16* __restrict__ fgb,
    float* __restrict__ out, unsigned* __restrict__ rowmax, int N, int D) {

    __shared__ __align__(16) __hip_bfloat16 lAk[BM * BK];
    __shared__ __align__(16) __hip_bfloat16 lBk[BN * BK];
    __shared__ __align__(16) __hip_bfloat16 lAg[BM * BK];
    __shared__ __align__(16) __hip_bfloat16 lBg[BN * BK];

    int t = threadIdx.x;
    int ntiles = N / BN;
    int bid = blockIdx.x;
    int by = bid / ntiles, bx = bid % ntiles;
    int r0 = by * BM, c0 = bx * BN;

    int w = t >> 6, l = t & 63;
    int wr = w >> 2, wc = w & 3;   // 2 x 4 wave grid; wave tile = 64 rows x 32 cols
    int lr = l & 15, lg = l >> 4;

    f32x4 acck[4][2], accg[4][2];
    f32x4 zero = {0.f, 0.f, 0.f, 0.f};
#pragma unroll
    for (int m = 0; m < 4; ++m)
#pragma unroll
        for (int n = 0; n < 2; ++n) { acck[m][n] = zero; accg[m][n] = zero; }

    const size_t rowbytes = (size_t)D * 2;

    for (int k0 = 0; k0 < D; k0 += BK) {
        // --- stage 4 tiles (A/B for k-gram and g-gram), swizzled source ---
#pragma unroll
        for (int c = 0; c < 2; ++c) {
            int o = (t + c * NTHREADS) * 16;           // linear byte offset in 16KB tile
            int row = o >> 7;                          // 128 B per LDS row (BK=64 bf16)
            int csw = (o & 127) ^ ((row & 7) << 4);    // inverse-swizzled source column
            size_t goffA = (size_t)(r0 + row) * rowbytes + (size_t)k0 * 2 + csw;
            size_t goffB = (size_t)(c0 + row) * rowbytes + (size_t)k0 * 2 + csw;
            int ldsoff = (w << 10) + (c << 13);        // wave-uniform dest base
            gload_lds16((const char*)fkb + goffA, (char*)lAk + ldsoff);
            gload_lds16((const char*)fkb + goffB, (char*)lBk + ldsoff);
            gload_lds16((const char*)fgb + goffA, (char*)lAg + ldsoff);
            gload_lds16((const char*)fgb + goffB, (char*)lBg + ldsoff);
        }
        __syncthreads();

#pragma unroll
        for (int kk = 0; kk < BK; kk += 32) {
            int kb = (kk + lg * 8) * 2;                // byte offset of this lane's 8 bf16
            short8 ak[4], ag[4], bk2[2], bg2[2];
#pragma unroll
            for (int m = 0; m < 4; ++m) {
                int row = wr * 64 + m * 16 + lr;
                int o = (row << 7) + kb;
                o ^= ((row & 7) << 4);                 // swizzled read
                ak[m] = *(const short8*)((const char*)lAk + o);
                ag[m] = *(const short8*)((const char*)lAg + o);
            }
#pragma unroll
            for (int n = 0; n < 2; ++n) {
                int row = wc * 32 + n * 16 + lr;
                int o = (row << 7) + kb;
                o ^= ((row & 7) << 4);
                bk2[n] = *(const short8*)((const char*)lBk + o);
                bg2[n] = *(const short8*)((const char*)lBg + o);
            }
#pragma unroll
            for (int m = 0; m < 4; ++m)
#pragma unroll
                for (int n = 0; n < 2; ++n) {
                    acck[m][n] = __builtin_amdgcn_mfma_f32_16x16x32_bf16(ak[m], bk2[n], acck[m][n], 0, 0, 0);
                    accg[m][n] = __builtin_amdgcn_mfma_f32_16x16x32_bf16(ag[m], bg2[n], accg[m][n], 0, 0, 0);
                }
        }
        __syncthreads();
    }

    // --- epilogue: ratio, diag, store, row max ---
    int gcoln[2];
#pragma unroll
    for (int n = 0; n < 2; ++n) gcoln[n] = c0 + wc * 32 + n * 16 + lr;

#pragma unroll
    for (int m = 0; m < 4; ++m) {
#pragma unroll
        for (int j = 0; j < 4; ++j) {
            int grow = r0 + wr * 64 + m * 16 + lg * 4 + j;   // C/D: row=(l>>4)*4+reg
            float pm = NEG_DIAG_F;
#pragma unroll
            for (int n = 0; n < 2; ++n) {
                float dk = acck[m][n][j];
                float dg = accg[m][n][j];
                float s = (dk + 1.0f + EPS_F) / (dg + 1.0f + EPS_F);
                if (grow == gcoln[n]) s = NEG_DIAG_F;
                out[(size_t)grow * N + gcoln[n]] = s;
                pm = fmaxf(pm, s);
            }
            // 16 lanes (same lg group) hold the 32 cols of this row: butterfly max
#pragma unroll
            for (int off = 1; off < 16; off <<= 1)
                pm = fmaxf(pm, __shfl_xor(pm, off, 64));
            if (lr == 0) atomicMax(&rowmax[grow], enc_f32(pm));
        }
    }
}

// ---------------------------------------------------------------------------
// Kernel 3: out = exp(s - rowmax[row]) in place, float4 grid-stride.
// ---------------------------------------------------------------------------
__global__ void finalize_kernel(float* __restrict__ out, const unsigned* __restrict__ rowmax, int N) {
    size_t total = (size_t)N * N / 4;
    int cols4 = N / 4;
    size_t stride = (size_t)gridDim.x * blockDim.x;
    for (size_t i = (size_t)blockIdx.x * blockDim.x + threadIdx.x; i < total; i += stride) {
        float4 v = reinterpret_cast<float4*>(out)[i];
        int row = (int)(i / cols4);
        float m = dec_f32(rowmax[row]);
        v.x = __expf(v.x - m);
        v.y = __expf(v.y - m);
        v.z = __expf(v.z - m);
        v.w = __expf(v.w - m);
        reinterpret_cast<float4*>(out)[i] = v;
    }
}

// ---------------------------------------------------------------------------
extern "C" void kernel_launch(void* const* d_in, const int* in_sizes, int n_in,
                              void* d_out, int out_size, void* d_ws, size_t ws_size,
                              hipStream_t stream) {
    const float* fk = (const float*)d_in[1];
    const float* fg = (const float*)d_in[2];
    float* out = (float*)d_out;

    int N = (int)llround(sqrt((double)out_size));   // 4096
    int D = in_sizes[1] / N;                        // 256

    char* ws = (char*)d_ws;
    __hip_bfloat16* fkb = (__hip_bfloat16*)ws;
    __hip_bfloat16* fgb = (__hip_bfloat16*)(ws + (size_t)N * D * 2);
    unsigned* rowmax = (unsigned*)(ws + (size_t)N * D * 4);

    norm_cast_kernel<<<N, D, 0, stream>>>(fk, fg, fkb, fgb, rowmax, N, D);

    int nt = N / BN;
    dual_gram_kernel<<<nt * nt, NTHREADS, 0, stream>>>(fkb, fgb, out, rowmax, N, D);

    finalize_kernel<<<2048, 256, 0, stream>>>(out, rowmax, N);
}